// Round 11
// baseline (1310.109 us; speedup 1.0000x reference)
//
#include <hip/hip_runtime.h>
#include <hip/hip_bf16.h>

// LSTM-LL v11: three-stage decomposition + LDS-only barriers.
//  K1  : layer-1 recurrence, whh1 in LDS, emb1 gate table; streams h1 -> g_h1.
//  K2a : layer-2 recurrence only, whh2 in LDS, wih2 streamed from L2, h1 read
//        direct from global; streams h2 -> g_h2.
//  K2b : logits+softmax+ll, fully parallel over (t,b), wave-local softmax.
// Loop barriers use s_waitcnt lgkmcnt(0)+s_barrier (no vmcnt drain: global
// stores/loads cross only kernel boundaries).
// B=8192, T=128, E=128, V=128, L=2.

typedef __bf16 bf16x8 __attribute__((ext_vector_type(8)));
typedef __bf16 bf16x4 __attribute__((ext_vector_type(4)));
typedef float  f32x4  __attribute__((ext_vector_type(4)));

#define LOG2E 1.4426950408889634f
#define LN2   0.6931471805599453f

#define LDS_BARRIER() asm volatile("s_waitcnt lgkmcnt(0)\n\ts_barrier" ::: "memory")

static __device__ __bf16 g_emb1[128 * 512];    // [v][gate*128+e] = (emb@Wih1^T + b1)*rowscale
static __device__ __bf16 g_woutbf[128 * 128];  // [v][e] * LOG2E
static __device__ __bf16 g_wih2bf[512 * 128];  // [gate*128+col][k] * rowscale (layer-2 Wih)
static __device__ __bf16 g_h1[(size_t)128 * 8192 * 128];  // slot 0 = h1init, slot t+1 = h1(t)
static __device__ __bf16 g_h2[(size_t)127 * 8192 * 128];  // slot t = h2(t), t = 0..126

__device__ __forceinline__ float frcp(float x) {
#if __has_builtin(__builtin_amdgcn_rcpf)
  return __builtin_amdgcn_rcpf(x);
#else
  return 1.0f / x;
#endif
}
__device__ __forceinline__ float fexp2(float x) {
#if __has_builtin(__builtin_amdgcn_exp2f)
  return __builtin_amdgcn_exp2f(x);
#else
  return exp2f(x);
#endif
}
__device__ __forceinline__ float flog2(float x) {
#if __has_builtin(__builtin_amdgcn_logf)
  return __builtin_amdgcn_logf(x);
#else
  return log2f(x);
#endif
}

// rotation swizzle for [*][128] bf16 LDS tiles: e -> (e + 8*(row&15)) & 127
__device__ __forceinline__ int hoff(int row, int e) {
  return row * 128 + ((e + ((row & 15) << 3)) & 127);
}

__global__ void prep_tables(const float* __restrict__ emb, const float* __restrict__ Wih,
                            const float* __restrict__ bih, const float* __restrict__ bhh,
                            const float* __restrict__ Wout) {
  __shared__ float embS[128 * 128];
  __shared__ float wS[32 * 128];
  const int tid = threadIdx.x, bc = blockIdx.x;
  for (int i = tid; i < 128 * 32; i += 512) ((f32x4*)embS)[i] = ((const f32x4*)emb)[i];
  for (int i = tid; i < 32 * 32; i += 512)
    ((f32x4*)wS)[i] = ((const f32x4*)(Wih + bc * 32 * 128))[i];
  {  // bf16 W_out table (pre-scaled by log2e)
    int idx = bc * 512 + tid;
    g_woutbf[idx * 2]     = (__bf16)(Wout[idx * 2] * LOG2E);
    g_woutbf[idx * 2 + 1] = (__bf16)(Wout[idx * 2 + 1] * LOG2E);
  }
  // bf16 layer-2 Wih table, pre-scaled per gate (g-gate x2)
  for (int i = bc * 512 + tid; i < 512 * 128; i += 16 * 512) {
    int gate = (i >> 14) & 3;
    float sc = (gate == 2) ? 2.0f * LOG2E : LOG2E;
    g_wih2bf[i] = (__bf16)(Wih[512 * 128 + i] * sc);
  }
  __syncthreads();
  const int v = tid & 127, c0 = (tid >> 7) * 8;
  const int rot = v & 31;
#pragma unroll
  for (int j = 0; j < 8; ++j) {
    int c = c0 + j;
    float s = 0.f;
    for (int k = 0; k < 128; ++k) {
      int kk = (k + rot) & 127;
      s += embS[v * 128 + kk] * wS[c * 128 + kk];
    }
    int col = bc * 32 + c;
    float sc = ((col >> 7) == 2) ? 2.0f * LOG2E : LOG2E;
    g_emb1[v * 512 + col] = (__bf16)((s + bih[col] + bhh[col]) * sc);
  }
}

// ============================ K1: layer-1 recurrence ============================
__global__ __launch_bounds__(512, 2) void lstm_l1(
    const float* __restrict__ state, const int* __restrict__ tokens,
    const float* __restrict__ W_ih, const float* __restrict__ W_hh,
    const float* __restrict__ b_ih, const float* __restrict__ b_hh) {
  __shared__ __align__(16) __bf16 whh1L[512 * 128];  // 128 KB, hoff
  __shared__ __align__(16) __bf16 h1L[2][32 * 128];  // 16 KB dbuf
  __shared__ unsigned char tokL[127][32];            // ~4 KB

  const int tid  = threadIdx.x;
  const int w    = tid >> 6;
  const int lane = tid & 63;
  const int lr   = lane & 15;
  const int lh   = lane >> 4;
  const int b0   = blockIdx.x * 32;
  const int col  = w * 16 + lr;
  const int koff = lh * 8;
  const int e0   = w * 16 + lh * 4;
  const float gscA[4] = {LOG2E, LOG2E, 2.0f * LOG2E, LOG2E};

  auto ldw8s = [&](const float* p, float sc) -> bf16x8 {
    f32x4 x0 = *(const f32x4*)p, x1 = *(const f32x4*)(p + 4);
    bf16x8 v;
#pragma unroll
    for (int j = 0; j < 4; ++j) { v[j] = (__bf16)(x0[j] * sc); v[4 + j] = (__bf16)(x1[j] * sc); }
    return v;
  };

  for (int i = tid; i < 512 * 16; i += 512) {
    int row = i >> 4, e = (i & 15) * 8;
    *(bf16x8*)(whh1L + hoff(row, e)) = ldw8s(W_hh + row * 128 + e, gscA[row >> 7]);
  }
  for (int i = tid; i < 127 * 32; i += 512) {
    int r = i & 31, t = i >> 5;
    tokL[t][r] = (unsigned char)tokens[(b0 + r) * 128 + t];
  }

  f32x4 acc[4][2];
  float c1[2][4] = {};

  auto ldB = [&](const __bf16* buf, int nf, int kc) -> bf16x8 {
    return *(const bf16x8*)(buf + hoff(nf * 16 + lr, kc * 32 + koff));
  };

  auto elem1 = [&](const f32x4* b4, __bf16* hout, __bf16* gout) {
#pragma unroll
    for (int nf = 0; nf < 2; ++nf) {
      bf16x4 hp;
#pragma unroll
      for (int j = 0; j < 4; ++j) {
        float gi = acc[0][nf][j] + b4[0][j];
        float gf = acc[1][nf][j] + b4[1][j];
        float gc = acc[2][nf][j] + b4[2][j];
        float go = acc[3][nf][j] + b4[3][j];
        float sf = frcp(1.f + fexp2(-gf));
        float si = frcp(1.f + fexp2(-gi));
        float tg = 1.f - 2.f * frcp(fexp2(gc) + 1.f);
        float cc = sf * c1[nf][j] + si * tg;
        c1[nf][j] = cc;
        float so = frcp(1.f + fexp2(-go));
        float tc = 1.f - 2.f * frcp(fexp2(2.f * LOG2E * cc) + 1.f);
        hp[j] = (__bf16)(so * tc);
      }
      int b = nf * 16 + lr;
      *(bf16x4*)(hout + hoff(b, e0)) = hp;
      *(bf16x4*)(gout + (size_t)(b0 + b) * 128 + e0) = hp;
    }
  };
  const f32x4 zf4 = {0.f, 0.f, 0.f, 0.f};
  const f32x4 zb4[4] = {zf4, zf4, zf4, zf4};

  __syncthreads();  // staging complete (full barrier, once)

  bf16x4 gv[2][4];
  auto gather = [&](int t) {
#pragma unroll
    for (int nf = 0; nf < 2; ++nf) {
      int tk = (int)tokL[t][nf * 16 + lr];
      const __bf16* pp = g_emb1 + tk * 512 + e0;
#pragma unroll
      for (int gg = 0; gg < 4; ++gg) gv[nf][gg] = *(const bf16x4*)(pp + gg * 128);
    }
  };
  gather(0);

  // init: h1init = LSTM1(state, h=c=0) -> h1L[0] + g_h1 slot 0
  {
#pragma unroll
    for (int gg = 0; gg < 4; ++gg)
#pragma unroll
      for (int nf = 0; nf < 2; ++nf) acc[gg][nf] = zf4;
#pragma unroll
    for (int kc = 0; kc < 4; ++kc) {
      bf16x8 s0 = ldw8s(state + (size_t)(b0 + lr) * 128 + kc * 32 + koff, 1.0f);
      bf16x8 s1 = ldw8s(state + (size_t)(b0 + 16 + lr) * 128 + kc * 32 + koff, 1.0f);
#pragma unroll
      for (int gg = 0; gg < 4; ++gg) {
        bf16x8 a = ldw8s(W_ih + (gg * 128 + col) * 128 + kc * 32 + koff, gscA[gg]);
        acc[gg][0] = __builtin_amdgcn_mfma_f32_16x16x32_bf16(a, s0, acc[gg][0], 0, 0, 0);
        acc[gg][1] = __builtin_amdgcn_mfma_f32_16x16x32_bf16(a, s1, acc[gg][1], 0, 0, 0);
      }
    }
    f32x4 bias1v4[4];
#pragma unroll
    for (int gg = 0; gg < 4; ++gg)
#pragma unroll
      for (int j = 0; j < 4; ++j)
        bias1v4[gg][j] = (b_ih[gg * 128 + e0 + j] + b_hh[gg * 128 + e0 + j]) * gscA[gg];
    elem1(bias1v4, h1L[0], g_h1);
    LDS_BARRIER();
  }

  // main loop: 1 LDS-barrier/step, chain operands all in LDS
#pragma unroll 1
  for (int t = 0; t < 127; ++t) {
    const __bf16* h1p = h1L[t & 1];
    __bf16* h1c = h1L[(t & 1) ^ 1];
#pragma unroll
    for (int gg = 0; gg < 4; ++gg)
#pragma unroll
      for (int nf = 0; nf < 2; ++nf)
#pragma unroll
        for (int j = 0; j < 4; ++j) acc[gg][nf][j] = (float)gv[nf][gg][j];
#pragma unroll
    for (int kc = 0; kc < 4; ++kc) {
      bf16x8 p0 = ldB(h1p, 0, kc), p1 = ldB(h1p, 1, kc);
#pragma unroll
      for (int gg = 0; gg < 4; ++gg) {
        bf16x8 a = *(const bf16x8*)(whh1L + hoff(gg * 128 + col, kc * 32 + koff));
        acc[gg][0] = __builtin_amdgcn_mfma_f32_16x16x32_bf16(a, p0, acc[gg][0], 0, 0, 0);
        acc[gg][1] = __builtin_amdgcn_mfma_f32_16x16x32_bf16(a, p1, acc[gg][1], 0, 0, 0);
      }
    }
    if (t + 1 < 127) gather(t + 1);
    elem1(zb4, h1c, g_h1 + (size_t)(t + 1) * 8192 * 128);
    LDS_BARRIER();
  }
}

// ======================= K2a: layer-2 recurrence only =======================
__global__ __launch_bounds__(512, 2) void lstm_l2rec(
    const float* __restrict__ W_hh, const float* __restrict__ b_ih,
    const float* __restrict__ b_hh) {
  __shared__ __align__(16) __bf16 whh2L[512 * 128];  // 128 KB, hoff
  __shared__ __align__(16) __bf16 h2L[2][32 * 128];  // 16 KB dbuf

  const int tid  = threadIdx.x;
  const int w    = tid >> 6;
  const int lane = tid & 63;
  const int lr   = lane & 15;
  const int lh   = lane >> 4;
  const int b0   = blockIdx.x * 32;
  const int col  = w * 16 + lr;
  const int koff = lh * 8;
  const int e0   = w * 16 + lh * 4;
  const float gscA[4] = {LOG2E, LOG2E, 2.0f * LOG2E, LOG2E};

  auto ldw8s = [&](const float* p, float sc) -> bf16x8 {
    f32x4 x0 = *(const f32x4*)p, x1 = *(const f32x4*)(p + 4);
    bf16x8 v;
#pragma unroll
    for (int j = 0; j < 4; ++j) { v[j] = (__bf16)(x0[j] * sc); v[4 + j] = (__bf16)(x1[j] * sc); }
    return v;
  };

  for (int i = tid; i < 512 * 16; i += 512) {
    int row = i >> 4, e = (i & 15) * 8;
    *(bf16x8*)(whh2L + hoff(row, e)) = ldw8s(W_hh + 512 * 128 + row * 128 + e, gscA[row >> 7]);
  }

  f32x4 bias2v4[4];
#pragma unroll
  for (int gg = 0; gg < 4; ++gg)
#pragma unroll
    for (int j = 0; j < 4; ++j)
      bias2v4[gg][j] = (b_ih[512 + gg * 128 + e0 + j] + b_hh[512 + gg * 128 + e0 + j]) * gscA[gg];

  float c2[2][4] = {};
  f32x4 acc[4][2];

  auto ldB = [&](const __bf16* buf, int nf, int kc) -> bf16x8 {
    return *(const bf16x8*)(buf + hoff(nf * 16 + lr, kc * 32 + koff));
  };
  // h1 B-frag straight from global stream (per-lane 16B)
  auto ldX = [&](int slot, int nf, int kc) -> bf16x8 {
    return *(const bf16x8*)(g_h1 + (size_t)slot * 8192 * 128 +
                            (size_t)(b0 + nf * 16 + lr) * 128 + kc * 32 + koff);
  };

  auto elem2 = [&](__bf16* hout, __bf16* gout) {
#pragma unroll
    for (int nf = 0; nf < 2; ++nf) {
      bf16x4 hp;
#pragma unroll
      for (int j = 0; j < 4; ++j) {
        float gi = acc[0][nf][j] + bias2v4[0][j];
        float gf = acc[1][nf][j] + bias2v4[1][j];
        float gc = acc[2][nf][j] + bias2v4[2][j];
        float go = acc[3][nf][j] + bias2v4[3][j];
        float sf = frcp(1.f + fexp2(-gf));
        float si = frcp(1.f + fexp2(-gi));
        float tg = 1.f - 2.f * frcp(fexp2(gc) + 1.f);
        float cc = sf * c2[nf][j] + si * tg;
        c2[nf][j] = cc;
        float so = frcp(1.f + fexp2(-go));
        float tc = 1.f - 2.f * frcp(fexp2(2.f * LOG2E * cc) + 1.f);
        hp[j] = (__bf16)(so * tc);
      }
      int b = nf * 16 + lr;
      *(bf16x4*)(hout + hoff(b, e0)) = hp;
      if (gout) *(bf16x4*)(gout + (size_t)(b0 + b) * 128 + e0) = hp;
    }
  };
  const f32x4 zf4 = {0.f, 0.f, 0.f, 0.f};

  __syncthreads();  // staging complete

  // init: h2init = LSTM2(h1init [slot 0], h=c=0) -> h2L[0] (not streamed)
  {
#pragma unroll
    for (int gg = 0; gg < 4; ++gg)
#pragma unroll
      for (int nf = 0; nf < 2; ++nf) acc[gg][nf] = zf4;
#pragma unroll
    for (int kc = 0; kc < 4; ++kc) {
      bf16x8 x0 = ldX(0, 0, kc), x1 = ldX(0, 1, kc);
#pragma unroll
      for (int gg = 0; gg < 4; ++gg) {
        bf16x8 a = *(const bf16x8*)(g_wih2bf + (size_t)(gg * 128 + col) * 128 + kc * 32 + koff);
        acc[gg][0] = __builtin_amdgcn_mfma_f32_16x16x32_bf16(a, x0, acc[gg][0], 0, 0, 0);
        acc[gg][1] = __builtin_amdgcn_mfma_f32_16x16x32_bf16(a, x1, acc[gg][1], 0, 0, 0);
      }
    }
    elem2(h2L[0], nullptr);
    LDS_BARRIER();
  }

  // main loop: 1 LDS-barrier/step; h2(t) -> h2L[cur] + g_h2 slot t
#pragma unroll 1
  for (int t = 0; t < 127; ++t) {
    const __bf16* prev = h2L[t & 1];
    __bf16* cur = h2L[(t & 1) ^ 1];

    // issue h1(t) loads early (slot t+1), consumed by wih2 MFMAs below
    bf16x8 x0[4], x1[4];
#pragma unroll
    for (int kc = 0; kc < 4; ++kc) { x0[kc] = ldX(t + 1, 0, kc); x1[kc] = ldX(t + 1, 1, kc); }

#pragma unroll
    for (int gg = 0; gg < 4; ++gg)
#pragma unroll
      for (int nf = 0; nf < 2; ++nf) acc[gg][nf] = zf4;
    // whh2 part first (pure LDS) to cover the x-load latency
#pragma unroll
    for (int kc = 0; kc < 4; ++kc) {
      bf16x8 y0 = ldB(prev, 0, kc), y1 = ldB(prev, 1, kc);
#pragma unroll
      for (int gg = 0; gg < 4; ++gg) {
        bf16x8 a2 = *(const bf16x8*)(whh2L + hoff(gg * 128 + col, kc * 32 + koff));
        acc[gg][0] = __builtin_amdgcn_mfma_f32_16x16x32_bf16(a2, y0, acc[gg][0], 0, 0, 0);
        acc[gg][1] = __builtin_amdgcn_mfma_f32_16x16x32_bf16(a2, y1, acc[gg][1], 0, 0, 0);
      }
    }
    // wih2 part (weights streamed from L2 per kc)
#pragma unroll
    for (int kc = 0; kc < 4; ++kc) {
#pragma unroll
      for (int gg = 0; gg < 4; ++gg) {
        bf16x8 a = *(const bf16x8*)(g_wih2bf + (size_t)(gg * 128 + col) * 128 + kc * 32 + koff);
        acc[gg][0] = __builtin_amdgcn_mfma_f32_16x16x32_bf16(a, x0[kc], acc[gg][0], 0, 0, 0);
        acc[gg][1] = __builtin_amdgcn_mfma_f32_16x16x32_bf16(a, x1[kc], acc[gg][1], 0, 0, 0);
      }
    }
    elem2(cur, g_h2 + (size_t)t * 8192 * 128);
    LDS_BARRIER();
  }
}

// =================== K2b: logits + softmax + ll (parallel) ===================
__global__ __launch_bounds__(512, 2) void logits_ll(
    const int* __restrict__ tokens, const float* __restrict__ b_out,
    float* __restrict__ out) {
  __shared__ __align__(16) __bf16 woL[128 * 128];  // 32 KB, hoff
  __shared__ unsigned char tokL[128][32];          // 4 KB
  __shared__ float llpart[8][32];

  const int tid  = threadIdx.x;
  const int w    = tid >> 6;
  const int lane = tid & 63;
  const int lr   = lane & 15;
  const int lh   = lane >> 4;
  const int b0   = blockIdx.x * 32;
  const int koff = lh * 8;

  for (int i = tid; i < 128 * 16; i += 512) {
    int row = i >> 4, e = (i & 15) * 8;
    *(bf16x8*)(woL + hoff(row, e)) = *(const bf16x8*)(g_woutbf + row * 128 + e);
  }
  for (int i = tid; i < 128 * 32; i += 512) {
    int r = i & 31, t = i >> 5;
    tokL[t][r] = (unsigned char)tokens[(b0 + r) * 128 + t];
  }

  // per-lane bias (log2-domain): bo8[mf][j] for v = mf*16 + lh*4 + j
  f32x4 bo8[8];
#pragma unroll
  for (int mf = 0; mf < 8; ++mf)
#pragma unroll
    for (int j = 0; j < 4; ++j) bo8[mf][j] = b_out[mf * 16 + lh * 4 + j] * LOG2E;

  __syncthreads();

  float ll0 = 0.f, ll1 = 0.f;  // rows lr and 16+lr

#pragma unroll 1
  for (int t = w; t < 127; t += 8) {
#pragma unroll
    for (int nf = 0; nf < 2; ++nf) {
      f32x4 acc8[8];
#pragma unroll
      for (int mf = 0; mf < 8; ++mf) acc8[mf] = bo8[mf];
#pragma unroll
      for (int kc = 0; kc < 4; ++kc) {
        bf16x8 y = *(const bf16x8*)(g_h2 + (size_t)t * 8192 * 128 +
                                    (size_t)(b0 + nf * 16 + lr) * 128 + kc * 32 + koff);
#pragma unroll
        for (int mf = 0; mf < 8; ++mf) {
          bf16x8 a = *(const bf16x8*)(woL + hoff(mf * 16 + lr, kc * 32 + koff));
          acc8[mf] = __builtin_amdgcn_mfma_f32_16x16x32_bf16(a, y, acc8[mf], 0, 0, 0);
        }
      }
      // row = b0 + nf*16 + lr ; lane holds v = mf*16 + lh*4 + j (32 of 128)
      float s = 0.f;
#pragma unroll
      for (int mf = 0; mf < 8; ++mf)
#pragma unroll
        for (int j = 0; j < 4; ++j) s += fexp2(acc8[mf][j]);
      s += __shfl_xor(s, 16);
      s += __shfl_xor(s, 32);  // full 128-v sum, all lanes
      int tgt = (int)tokL[t + 1][nf * 16 + lr];
      float contrib = 0.f;
      if (((tgt >> 2) & 3) == lh) {
        int j = tgt & 3;
        float lvs = 0.f;
#pragma unroll
        for (int mf = 0; mf < 8; ++mf)
          if ((tgt >> 4) == mf)
            lvs = (j & 2) ? ((j & 1) ? acc8[mf][3] : acc8[mf][2])
                          : ((j & 1) ? acc8[mf][1] : acc8[mf][0]);
        contrib = lvs - flog2(s);
      }
      if (nf == 0) ll0 += contrib; else ll1 += contrib;
    }
  }

  // reduce across lh lanes, then across waves
  ll0 += __shfl_xor(ll0, 16); ll0 += __shfl_xor(ll0, 32);
  ll1 += __shfl_xor(ll1, 16); ll1 += __shfl_xor(ll1, 32);
  if (lh == 0) { llpart[w][lr] = ll0; llpart[w][16 + lr] = ll1; }
  __syncthreads();
  if (tid < 32) {
    float s = 0.f;
#pragma unroll
    for (int ww = 0; ww < 8; ++ww) s += llpart[ww][tid];
    out[b0 + tid] = s * LN2;
  }
}

extern "C" void kernel_launch(void* const* d_in, const int* in_sizes, int n_in,
                              void* d_out, int out_size, void* d_ws, size_t ws_size,
                              hipStream_t stream) {
  const float* state  = (const float*)d_in[0];
  const int*   tokens = (const int*)d_in[1];
  const float* emb    = (const float*)d_in[2];
  const float* Wih    = (const float*)d_in[3];
  const float* Whh    = (const float*)d_in[4];
  const float* bih    = (const float*)d_in[5];
  const float* bhh    = (const float*)d_in[6];
  const float* Wout   = (const float*)d_in[7];
  const float* bout   = (const float*)d_in[8];
  float* out = (float*)d_out;

  prep_tables<<<16, 512, 0, stream>>>(emb, Wih, bih, bhh, Wout);
  lstm_l1<<<256, 512, 0, stream>>>(state, tokens, Wih, Whh, bih, bhh);
  lstm_l2rec<<<256, 512, 0, stream>>>(Whh, bih, bhh);
  logits_ll<<<256, 512, 0, stream>>>(tokens, bout, out);
}